// Round 1
// baseline (343.558 us; speedup 1.0000x reference)
//
#include <hip/hip_runtime.h>
#include <hip/hip_bf16.h>
#include <math.h>

#define D_L   256
#define L_L   64
#define K_C   8
#define BATCH 2048
#define NTOT  16384
#define ENC_COLS 1536
#define DEC_COLS 6144
#define LOG2PI 1.8378770664093453f

// workspace layout (float offsets)
#define OFF_PRED_E 0
#define OFF_H      (BATCH * ENC_COLS)        // 3,145,728
#define OFF_LQE    (OFF_H + NTOT * L_L)      // 4,194,304
#define OFF_LD     (OFF_LQE + NTOT)          // 4,210,688
// total = 4,227,072 floats = 16.9 MB

// ---------------------------------------------------------------------------
// Kernel 1: pred_e = x @ W_e + b_e   (2048 x 1536)
// grid (2,128), block 256. Block: 16 rows x 768 cols. Thread: 16 rows x 3 cols.
// ---------------------------------------------------------------------------
__global__ __launch_bounds__(256) void k_enc_gemm(
    const float* __restrict__ x, const float* __restrict__ We,
    const float* __restrict__ be, float* __restrict__ pe)
{
  __shared__ float xsT[D_L][16];   // [i][row], rows 64B-aligned
  const int tid = threadIdx.x;
  const int bx = blockIdx.x;       // col half (0..1)
  const int by = blockIdx.y;       // row group (0..127)

  for (int idx = tid; idx < 16 * D_L; idx += 256) {
    const int r = idx >> 8;        // 0..15
    const int i = idx & 255;
    xsT[i][r] = x[(size_t)(by * 16 + r) * D_L + i];
  }
  __syncthreads();

  for (int cc = 0; cc < 3; ++cc) {
    const int c = bx * 768 + cc * 256 + tid;
    float acc[16];
    const float bias = be[c];
    #pragma unroll
    for (int r = 0; r < 16; ++r) acc[r] = bias;
    const float* wcol = We + c;
    #pragma unroll 4
    for (int i = 0; i < D_L; ++i) {
      const float w = wcol[(size_t)i * ENC_COLS];
      #pragma unroll
      for (int r = 0; r < 16; ++r) acc[r] = fmaf(xsT[i][r], w, acc[r]);
    }
    #pragma unroll
    for (int r = 0; r < 16; ++r)
      pe[(size_t)(by * 16 + r) * ENC_COLS + c] = acc[r];
  }
}

// ---------------------------------------------------------------------------
// Kernel 2: encoder postprocess. One wave per batch row b, lane = latent dim l.
// Computes h[n,l], and lqe[n] = L_q - L_e (without the cancelling const terms).
// grid 512, block 256 (4 waves -> 4 b's).
// ---------------------------------------------------------------------------
__global__ __launch_bounds__(256) void k_enc_post(
    const float* __restrict__ pe, const float* __restrict__ ue,
    const float* __restrict__ rr, float* __restrict__ h,
    float* __restrict__ lqe)
{
  const int lane = threadIdx.x & 63;                 // l
  const int b = blockIdx.x * 4 + (threadIdx.x >> 6); // batch row
  const float* row = pe + (size_t)b * ENC_COLS + lane;

  float m[8], p[8], a[8];
  #pragma unroll
  for (int k = 0; k < K_C; ++k) {
    m[k] = row[k * 64];
    p[k] = row[512 + k * 64];
    a[k] = row[1024 + k * 64];
  }
  float amax = a[0];
  #pragma unroll
  for (int k = 1; k < K_C; ++k) amax = fmaxf(amax, a[k]);
  float sa = 0.f;
  #pragma unroll
  for (int k = 0; k < K_C; ++k) sa += __expf(a[k] - amax);
  const float lse_a = amax + __logf(sa);

  float cum[8];
  {
    float cs = 0.f;
    #pragma unroll
    for (int k = 0; k < K_C; ++k) { cs += __expf(a[k] - lse_a); cum[k] = cs; }
  }
  float ep[8];
  #pragma unroll
  for (int k = 0; k < K_C; ++k) ep[k] = __expf(p[k]);

  for (int j = 0; j < 8; ++j) {
    const int n = b + BATCH * j;
    const float rv = rr[(size_t)n * L_L + lane];
    const float uv = ue[(size_t)n * L_L + lane];

    int idx = 0;
    #pragma unroll
    for (int k = 0; k < K_C; ++k) idx += (rv > cum[k]) ? 1 : 0;
    idx = min(idx, K_C - 1);

    float msel = m[0], psel = p[0];
    #pragma unroll
    for (int k = 1; k < K_C; ++k) {
      const bool sel = (idx == k);
      msel = sel ? m[k] : msel;
      psel = sel ? p[k] : psel;
    }
    const float hv = fmaf(__expf(-0.5f * psel), uv, msel);
    h[(size_t)n * L_L + lane] = hv;

    float st = 0.f;
    #pragma unroll
    for (int k = 0; k < K_C; ++k) {
      const float dd = hv - m[k];
      const float t = a[k] + 0.5f * p[k] - 0.5f * ep[k] * dd * dd;
      st += __expf(t);
    }
    // per-lane contribution to L_q - L_e  (const terms cancel)
    float contrib = -0.5f * hv * hv - (__logf(st + 1e-30f) - lse_a);
    #pragma unroll
    for (int off = 32; off; off >>= 1) contrib += __shfl_xor(contrib, off, 64);
    if (lane == 0) lqe[n] = contrib;
  }
}

// ---------------------------------------------------------------------------
// Kernel 3: zero L_d accumulators
// ---------------------------------------------------------------------------
__global__ void k_zero(float* __restrict__ Ld)
{
  Ld[blockIdx.x * 256 + threadIdx.x] = 0.f;
}

// ---------------------------------------------------------------------------
// Kernel 4: fused decoder GEMM + mixture epilogue.
// Block: 64 rows (n) x 64 cols (d), streaming over k = 0..7 components.
// Thread micro-tile 4x4. Partial sum over this block's d-range -> atomicAdd.
// grid (4, 256), block 256.
// ---------------------------------------------------------------------------
__global__ __launch_bounds__(256) void k_dec(
    const float* __restrict__ h, const float* __restrict__ x,
    const float* __restrict__ Wd, const float* __restrict__ bd,
    float* __restrict__ Ld)
{
  __shared__ float hT[64][68];   // [i][r], padded: rows 272B (16B-aligned)
  __shared__ float wm[64][64];
  __shared__ float wp[64][64];
  __shared__ float wa[64][64];

  const int tid = threadIdx.x;
  const int tx = tid & 15;        // d-quad
  const int ty = tid >> 4;        // row-quad
  const int d0 = blockIdx.x * 64;
  const int n0 = blockIdx.y * 64;

  // stage h tile, transposed
  for (int idx = tid; idx < 64 * 64; idx += 256) {
    const int r = idx >> 6;
    const int i = idx & 63;
    hT[i][r] = h[(size_t)(n0 + r) * L_L + i];
  }

  // x_rep values for this thread's 4x4 outputs
  float xv[4][4];
  #pragma unroll
  for (int r = 0; r < 4; ++r) {
    const float* xp = x + (size_t)((n0 + ty * 4 + r) & (BATCH - 1)) * D_L + d0 + tx * 4;
    #pragma unroll
    for (int c = 0; c < 4; ++c) xv[r][c] = xp[c];
  }

  float s_a[4][4], s_t[4][4];
  #pragma unroll
  for (int r = 0; r < 4; ++r)
    #pragma unroll
    for (int c = 0; c < 4; ++c) { s_a[r][c] = 0.f; s_t[r][c] = 0.f; }

  for (int k = 0; k < K_C; ++k) {
    __syncthreads();   // also guards hT completion on k==0
    {
      const int c4 = tx * 4;
      const float* wbase = Wd + (size_t)k * 256 + d0 + c4;
      #pragma unroll
      for (int s = 0; s < 4; ++s) {
        const int i = ty + s * 16;
        const float* wrow = wbase + (size_t)i * DEC_COLS;
        *(float4*)&wm[i][c4] = *(const float4*)(wrow);
        *(float4*)&wp[i][c4] = *(const float4*)(wrow + 2048);
        *(float4*)&wa[i][c4] = *(const float4*)(wrow + 4096);
      }
    }
    __syncthreads();

    float am[4][4], ap2[4][4], aa[4][4];
    #pragma unroll
    for (int r = 0; r < 4; ++r)
      #pragma unroll
      for (int c = 0; c < 4; ++c) { am[r][c] = 0.f; ap2[r][c] = 0.f; aa[r][c] = 0.f; }

    #pragma unroll 4
    for (int i = 0; i < 64; ++i) {
      const float4 hv4 = *(const float4*)(&hT[i][ty * 4]);
      const float4 m4  = *(const float4*)(&wm[i][tx * 4]);
      const float4 p4  = *(const float4*)(&wp[i][tx * 4]);
      const float4 a4  = *(const float4*)(&wa[i][tx * 4]);
      const float hr[4] = {hv4.x, hv4.y, hv4.z, hv4.w};
      const float mc[4] = {m4.x, m4.y, m4.z, m4.w};
      const float pc[4] = {p4.x, p4.y, p4.z, p4.w};
      const float ac[4] = {a4.x, a4.y, a4.z, a4.w};
      #pragma unroll
      for (int r = 0; r < 4; ++r)
        #pragma unroll
        for (int c = 0; c < 4; ++c) {
          am[r][c]  = fmaf(hr[r], mc[c], am[r][c]);
          ap2[r][c] = fmaf(hr[r], pc[c], ap2[r][c]);
          aa[r][c]  = fmaf(hr[r], ac[c], aa[r][c]);
        }
    }

    const float* bb = bd + k * 256 + d0 + tx * 4;
    float bm[4], bp2[4], ba2[4];
    #pragma unroll
    for (int c = 0; c < 4; ++c) {
      bm[c] = bb[c]; bp2[c] = bb[2048 + c]; ba2[c] = bb[4096 + c];
    }

    #pragma unroll
    for (int r = 0; r < 4; ++r)
      #pragma unroll
      for (int c = 0; c < 4; ++c) {
        const float lm = am[r][c] + bm[c];
        const float lp = ap2[r][c] + bp2[c];
        const float la = aa[r][c] + ba2[c];
        const float dd = xv[r][c] - lm;
        const float t  = la + 0.5f * lp - 0.5f * __expf(lp) * dd * dd;
        s_a[r][c] += __expf(la);
        s_t[r][c] += __expf(t);
      }
  }

  // sum this thread's 4 d's per row, reduce over the 16 tx lanes, accumulate
  #pragma unroll
  for (int r = 0; r < 4; ++r) {
    float v = 0.f;
    #pragma unroll
    for (int c = 0; c < 4; ++c)
      v += __logf(s_t[r][c] + 1e-30f) - __logf(s_a[r][c]);
    #pragma unroll
    for (int off = 1; off < 16; off <<= 1) v += __shfl_xor(v, off, 64);
    if (tx == 0) atomicAdd(&Ld[n0 + ty * 4 + r], v);
  }
}

// ---------------------------------------------------------------------------
// Kernel 5: final reduction -> scalar loss
// loss = -mean(Ld_part + lqe) + 0.5*D*log(2pi)
// ---------------------------------------------------------------------------
__global__ __launch_bounds__(1024) void k_final(
    const float* __restrict__ Ld, const float* __restrict__ lqe,
    float* __restrict__ out)
{
  const int tid = threadIdx.x;
  float s = 0.f;
  for (int n = tid; n < NTOT; n += 1024) s += Ld[n] + lqe[n];
  #pragma unroll
  for (int off = 32; off; off >>= 1) s += __shfl_xor(s, off, 64);
  __shared__ float red[16];
  if ((tid & 63) == 0) red[tid >> 6] = s;
  __syncthreads();
  if (tid < 64) {
    float v = (tid < 16) ? red[tid] : 0.f;
    #pragma unroll
    for (int off = 8; off; off >>= 1) v += __shfl_xor(v, off, 64);
    if (tid == 0) out[0] = -(v / (float)NTOT) + 128.0f * LOG2PI;
  }
}

// ---------------------------------------------------------------------------
extern "C" void kernel_launch(void* const* d_in, const int* in_sizes, int n_in,
                              void* d_out, int out_size, void* d_ws, size_t ws_size,
                              hipStream_t stream)
{
  const float* x  = (const float*)d_in[0];
  const float* We = (const float*)d_in[1];
  const float* be = (const float*)d_in[2];
  const float* Wd = (const float*)d_in[3];
  const float* bd = (const float*)d_in[4];
  const float* ue = (const float*)d_in[5];
  const float* rr = (const float*)d_in[6];
  float* out = (float*)d_out;

  float* ws  = (float*)d_ws;
  float* pe  = ws + OFF_PRED_E;
  float* h   = ws + OFF_H;
  float* lqe = ws + OFF_LQE;
  float* Ld  = ws + OFF_LD;

  k_enc_gemm<<<dim3(2, 128), 256, 0, stream>>>(x, We, be, pe);
  k_zero<<<dim3(NTOT / 256), 256, 0, stream>>>(Ld);
  k_enc_post<<<dim3(BATCH / 4), 256, 0, stream>>>(pe, ue, rr, h, lqe);
  k_dec<<<dim3(4, 256), 256, 0, stream>>>(h, x, Wd, bd, Ld);
  k_final<<<dim3(1), 1024, 0, stream>>>(Ld, lqe, out);
}

// Round 2
// 140.330 us; speedup vs baseline: 2.4482x; 2.4482x over previous
//
#include <hip/hip_runtime.h>
#include <hip/hip_bf16.h>
#include <math.h>

#define D_L   256
#define L_L   64
#define K_C   8
#define BATCH 2048
#define NTOT  16384
#define ENC_COLS 1536
#define DEC_COLS 6144
#define LOG2PI 1.8378770664093453f

typedef __attribute__((ext_vector_type(8)))  short  short8;
typedef __attribute__((ext_vector_type(8)))  unsigned short ushort8;
typedef __attribute__((ext_vector_type(4)))  float  float4_;
typedef __attribute__((ext_vector_type(16))) float  float16_;

// workspace layout (float offsets); total 16.65 MB <= round-0's 16.9 MB footprint
#define OFF_PE   0                           // 2048*1536 f32
#define OFF_H    (BATCH * ENC_COLS)          // 16384*64 bf16 (524288 floats)
#define OFF_LQE  (OFF_H + NTOT * L_L / 2)    // 16384 f32
#define OFF_LD   (OFF_LQE + NTOT)            // 16384 f32
#define OFF_XB   (OFF_LD + NTOT)             // 2048*256 bf16 (262144 floats); aliased by WdT later
#define OFF_WET  (OFF_XB + BATCH * D_L / 2)  // 1536*256 bf16 (196608 floats)
#define OFF_WDT  OFF_XB                      // 6144*64 bf16 — written AFTER enc gemm consumes xb

__device__ __forceinline__ unsigned short f2bf(float f) {
  unsigned u = __float_as_uint(f);
  unsigned r = (u + 0x7fffu + ((u >> 16) & 1u)) >> 16;
  return (unsigned short)r;
}

// ---------------------------------------------------------------------------
// convert x (2048x256 f32) -> bf16, 8 elems/thread. grid 256 x 256 thr.
// ---------------------------------------------------------------------------
__global__ __launch_bounds__(256) void k_cvt_x(
    const float* __restrict__ in, unsigned short* __restrict__ out)
{
  const size_t idx = ((size_t)blockIdx.x * 256 + threadIdx.x) * 8;
  float4_ a = *(const float4_*)(in + idx);
  float4_ b = *(const float4_*)(in + idx + 4);
  ushort8 o;
  o[0] = f2bf(a[0]); o[1] = f2bf(a[1]); o[2] = f2bf(a[2]); o[3] = f2bf(a[3]);
  o[4] = f2bf(b[0]); o[5] = f2bf(b[1]); o[6] = f2bf(b[2]); o[7] = f2bf(b[3]);
  *(ushort8*)(out + idx) = o;
}

// ---------------------------------------------------------------------------
// transpose-convert: in f32 [R][C] -> out bf16 [C][R]. grid (C/64, R/64).
// ---------------------------------------------------------------------------
__global__ __launch_bounds__(256) void k_cvt_T(
    const float* __restrict__ in, unsigned short* __restrict__ out,
    int R, int C)
{
  __shared__ float tile[64][65];
  const int t = threadIdx.x;
  const int c0 = blockIdx.x * 64, r0 = blockIdx.y * 64;
  {
    const int tr = t >> 2, tc = (t & 3) * 16;
    const float* src = in + (size_t)(r0 + tr) * C + c0 + tc;
    #pragma unroll
    for (int i = 0; i < 4; ++i) {
      float4_ v = *(const float4_*)(src + 4 * i);
      #pragma unroll
      for (int j = 0; j < 4; ++j) tile[tr][tc + 4 * i + j] = v[j];
    }
  }
  __syncthreads();
  const int c = t >> 2, ks = (t & 3) * 16;
  unsigned short tmp[16];
  #pragma unroll
  for (int j = 0; j < 16; ++j) tmp[j] = f2bf(tile[ks + j][c]);
  unsigned short* dst = out + (size_t)(c0 + c) * R + r0 + ks;
  ushort8 o0, o1;
  #pragma unroll
  for (int j = 0; j < 8; ++j) { o0[j] = tmp[j]; o1[j] = tmp[8 + j]; }
  *(ushort8*)dst = o0;
  *(ushort8*)(dst + 8) = o1;
}

// ---------------------------------------------------------------------------
// Encoder GEMM (MFMA 16x16x32 bf16): pred_e = x @ W_e + b_e  (2048x1536, K=256)
// block 64x64 tile, 4 waves (wave = 16 rows x 64 cols). grid (24, 32).
// ---------------------------------------------------------------------------
__global__ __launch_bounds__(256) void k_enc_mfma(
    const unsigned short* __restrict__ xb, const unsigned short* __restrict__ WeT,
    const float* __restrict__ be, float* __restrict__ pe)
{
  __shared__ __align__(16) unsigned short as[64 * 264];  // pitch 264: 16B-aligned rows, 2-way banks
  __shared__ __align__(16) unsigned short bs[64 * 264];
  const int t = threadIdx.x;
  const int w = t >> 6, l = t & 63;
  const int m0 = blockIdx.y * 64, c0 = blockIdx.x * 64;

  #pragma unroll
  for (int p = 0; p < 8; ++p) {
    const int ci = t + 256 * p;
    const int row = ci >> 5, off = (ci & 31) * 8;
    *(ushort8*)&as[row * 264 + off] = *(const ushort8*)(xb + (size_t)(m0 + row) * 256 + off);
    *(ushort8*)&bs[row * 264 + off] = *(const ushort8*)(WeT + (size_t)(c0 + row) * 256 + off);
  }
  __syncthreads();

  const int lr = l & 15, lq = l >> 4;
  float4_ acc[4] = {};
  const unsigned short* aponce = &as[(w * 16 + lr) * 264 + lq * 8];
  #pragma unroll
  for (int kk = 0; kk < 8; ++kk) {
    short8 a = *(const short8*)(aponce + kk * 32);
    #pragma unroll
    for (int ct = 0; ct < 4; ++ct) {
      short8 b = *(const short8*)(&bs[(ct * 16 + lr) * 264 + lq * 8 + kk * 32]);
      acc[ct] = __builtin_amdgcn_mfma_f32_16x16x32_bf16(a, b, acc[ct], 0, 0, 0);
    }
  }
  #pragma unroll
  for (int ct = 0; ct < 4; ++ct) {
    const int c = c0 + ct * 16 + lr;
    const float bias = be[c];
    #pragma unroll
    for (int reg = 0; reg < 4; ++reg) {
      const int m = m0 + w * 16 + lq * 4 + reg;
      pe[(size_t)m * ENC_COLS + c] = acc[ct][reg] + bias;
    }
  }
}

// ---------------------------------------------------------------------------
// Encoder post: sample + h (bf16 out) + (L_q - L_e). One wave per batch row.
// ---------------------------------------------------------------------------
__global__ __launch_bounds__(256) void k_enc_post(
    const float* __restrict__ pe, const float* __restrict__ ue,
    const float* __restrict__ rr, unsigned short* __restrict__ h,
    float* __restrict__ lqe)
{
  const int lane = threadIdx.x & 63;
  const int b = blockIdx.x * 4 + (threadIdx.x >> 6);
  const float* row = pe + (size_t)b * ENC_COLS + lane;

  float m[8], p[8], a[8];
  #pragma unroll
  for (int k = 0; k < K_C; ++k) {
    m[k] = row[k * 64]; p[k] = row[512 + k * 64]; a[k] = row[1024 + k * 64];
  }
  float amax = a[0];
  #pragma unroll
  for (int k = 1; k < K_C; ++k) amax = fmaxf(amax, a[k]);
  float sa = 0.f;
  #pragma unroll
  for (int k = 0; k < K_C; ++k) sa += __expf(a[k] - amax);
  const float lse_a = amax + __logf(sa);

  float cum[8];
  {
    float cs = 0.f;
    #pragma unroll
    for (int k = 0; k < K_C; ++k) { cs += __expf(a[k] - lse_a); cum[k] = cs; }
  }
  float ep[8];
  #pragma unroll
  for (int k = 0; k < K_C; ++k) ep[k] = __expf(p[k]);

  for (int j = 0; j < 8; ++j) {
    const int n = b + BATCH * j;
    const float rv = rr[(size_t)n * L_L + lane];
    const float uv = ue[(size_t)n * L_L + lane];
    int idx = 0;
    #pragma unroll
    for (int k = 0; k < K_C; ++k) idx += (rv > cum[k]) ? 1 : 0;
    idx = min(idx, K_C - 1);
    float msel = m[0], psel = p[0];
    #pragma unroll
    for (int k = 1; k < K_C; ++k) {
      const bool sel = (idx == k);
      msel = sel ? m[k] : msel;
      psel = sel ? p[k] : psel;
    }
    const float hv = fmaf(__expf(-0.5f * psel), uv, msel);
    h[(size_t)n * L_L + lane] = f2bf(hv);

    float st = 0.f;
    #pragma unroll
    for (int k = 0; k < K_C; ++k) {
      const float dd = hv - m[k];
      const float tt = a[k] + 0.5f * p[k] - 0.5f * ep[k] * dd * dd;
      st += __expf(tt);
    }
    float contrib = -0.5f * hv * hv - (__logf(st + 1e-30f) - lse_a);
    #pragma unroll
    for (int off = 32; off; off >>= 1) contrib += __shfl_xor(contrib, off, 64);
    if (lane == 0) lqe[n] = contrib;
  }
}

__global__ void k_zero(float* __restrict__ Ld)
{
  Ld[blockIdx.x * 256 + threadIdx.x] = 0.f;
}

// ---------------------------------------------------------------------------
// Decoder: MFMA 32x32x16 bf16 GEMM fused with mixture epilogue.
// Block = 64 rows x 64 d. Wave = 32 rows x 32 d, computing m/p/a tiles.
// Stream over the 8 components. grid (4, 256).
// ---------------------------------------------------------------------------
__global__ __launch_bounds__(256) void k_dec_mfma(
    const unsigned short* __restrict__ hb, const float* __restrict__ x,
    const unsigned short* __restrict__ WdT, const float* __restrict__ bd,
    float* __restrict__ Ld)
{
  __shared__ __align__(16) unsigned short hs[64 * 72];    // A: [row][k], pitch 72
  __shared__ __align__(16) unsigned short bT[192 * 72];   // B^T: [col][k], cols = 3 params x 64 d
  __shared__ float biasLds[192];

  const int t = threadIdx.x;
  const int w = t >> 6, l = t & 63;
  const int n0 = blockIdx.y * 64, d0 = blockIdx.x * 64;
  const int col = l & 31;        // d within 32-wide patch
  const int q = l >> 5;          // half-wave
  const int rg = w >> 1;         // row-group (0/1)
  const int dg = w & 1;          // d-group (0/1)

  // stage A (h tile: 64 rows x 64 k, contiguous 8KB in global)
  #pragma unroll
  for (int p = 0; p < 2; ++p) {
    const int ci = t + 256 * p;
    const int row = ci >> 3, off = (ci & 7) * 8;
    *(ushort8*)&hs[row * 72 + off] = *(const ushort8*)(hb + (size_t)(n0 + row) * 64 + off);
  }

  // preload x values for this lane's 16 output elements (same across components)
  float xv[16];
  #pragma unroll
  for (int e = 0; e < 16; ++e) {
    const int rr_ = (e & 3) + 8 * (e >> 2) + 4 * q;
    const int n = n0 + rg * 32 + rr_;
    xv[e] = x[(size_t)(n & (BATCH - 1)) * D_L + d0 + dg * 32 + col];
  }

  float s_a[16], s_t[16];
  #pragma unroll
  for (int e = 0; e < 16; ++e) { s_a[e] = 0.f; s_t[e] = 0.f; }

  const unsigned short* arow = &hs[(rg * 32 + col) * 72 + q * 8];  // A: m = lane&31
  const unsigned short* brow = &bT[(dg * 32 + col) * 72 + q * 8];  // B: n = lane&31

  for (int kc = 0; kc < K_C; ++kc) {
    __syncthreads();
    // stage B^T for this component: 3 params x 64 cols x 64 k
    #pragma unroll
    for (int p = 0; p < 6; ++p) {
      const int ci = t + 256 * p;
      const int c = ci >> 3, off = (ci & 7) * 8;
      const int param = c >> 6, dd = c & 63;
      *(ushort8*)&bT[c * 72 + off] =
          *(const ushort8*)(WdT + ((size_t)param * 2048 + kc * 256 + d0 + dd) * 64 + off);
    }
    if (t < 192) biasLds[t] = bd[(t >> 6) * 2048 + kc * 256 + d0 + (t & 63)];
    __syncthreads();

    float16_ am = {}, ap = {}, aa = {};
    #pragma unroll
    for (int st = 0; st < 4; ++st) {
      short8 af  = *(const short8*)(arow + st * 16);
      short8 bfm = *(const short8*)(brow + st * 16);
      short8 bfp = *(const short8*)(brow + 64 * 72 + st * 16);
      short8 bfa = *(const short8*)(brow + 128 * 72 + st * 16);
      am = __builtin_amdgcn_mfma_f32_32x32x16_bf16(af, bfm, am, 0, 0, 0);
      ap = __builtin_amdgcn_mfma_f32_32x32x16_bf16(af, bfp, ap, 0, 0, 0);
      aa = __builtin_amdgcn_mfma_f32_32x32x16_bf16(af, bfa, aa, 0, 0, 0);
    }

    const float bm_ = biasLds[dg * 32 + col];
    const float bp_ = biasLds[64 + dg * 32 + col];
    const float ba_ = biasLds[128 + dg * 32 + col];
    #pragma unroll
    for (int e = 0; e < 16; ++e) {
      const float lm = am[e] + bm_;
      const float lp = ap[e] + bp_;
      const float la = aa[e] + ba_;
      const float dd = xv[e] - lm;
      const float ex = __expf(lp);
      const float tt = fmaf(0.5f, lp, la) - 0.5f * ex * dd * dd;
      s_a[e] += __expf(la);
      s_t[e] += __expf(tt);
    }
  }

  // per-row reduce over the 32 d's held across the half-wave, then atomic
  #pragma unroll
  for (int e = 0; e < 16; ++e) {
    float v = __logf(s_t[e] + 1e-30f) - __logf(s_a[e]);
    v += __shfl_xor(v, 1, 64);
    v += __shfl_xor(v, 2, 64);
    v += __shfl_xor(v, 4, 64);
    v += __shfl_xor(v, 8, 64);
    v += __shfl_xor(v, 16, 64);
    if (col == 0) {
      const int rr_ = (e & 3) + 8 * (e >> 2) + 4 * q;
      atomicAdd(&Ld[n0 + rg * 32 + rr_], v);
    }
  }
}

// ---------------------------------------------------------------------------
// final reduction -> scalar loss
// ---------------------------------------------------------------------------
__global__ __launch_bounds__(1024) void k_final(
    const float* __restrict__ Ld, const float* __restrict__ lqe,
    float* __restrict__ out)
{
  const int tid = threadIdx.x;
  float s = 0.f;
  for (int n = tid; n < NTOT; n += 1024) s += Ld[n] + lqe[n];
  #pragma unroll
  for (int off = 32; off; off >>= 1) s += __shfl_xor(s, off, 64);
  __shared__ float red[16];
  if ((tid & 63) == 0) red[tid >> 6] = s;
  __syncthreads();
  if (tid < 64) {
    float v = (tid < 16) ? red[tid] : 0.f;
    #pragma unroll
    for (int off = 8; off; off >>= 1) v += __shfl_xor(v, off, 64);
    if (tid == 0) out[0] = -(v / (float)NTOT) + 128.0f * LOG2PI;
  }
}

// ---------------------------------------------------------------------------
extern "C" void kernel_launch(void* const* d_in, const int* in_sizes, int n_in,
                              void* d_out, int out_size, void* d_ws, size_t ws_size,
                              hipStream_t stream)
{
  const float* x  = (const float*)d_in[0];
  const float* We = (const float*)d_in[1];
  const float* be = (const float*)d_in[2];
  const float* Wd = (const float*)d_in[3];
  const float* bd = (const float*)d_in[4];
  const float* ue = (const float*)d_in[5];
  const float* rr = (const float*)d_in[6];
  float* out = (float*)d_out;

  float* ws = (float*)d_ws;
  float* pe            = ws + OFF_PE;
  unsigned short* h    = (unsigned short*)(ws + OFF_H);
  float* lqe           = ws + OFF_LQE;
  float* Ld            = ws + OFF_LD;
  unsigned short* xb   = (unsigned short*)(ws + OFF_XB);
  unsigned short* WeT  = (unsigned short*)(ws + OFF_WET);
  unsigned short* WdT  = (unsigned short*)(ws + OFF_WDT);  // aliases xb region

  k_cvt_x<<<dim3(256), 256, 0, stream>>>(x, xb);
  k_cvt_T<<<dim3(ENC_COLS / 64, D_L / 64), 256, 0, stream>>>(We, WeT, D_L, ENC_COLS);
  k_zero<<<dim3(NTOT / 256), 256, 0, stream>>>(Ld);
  k_enc_mfma<<<dim3(ENC_COLS / 64, BATCH / 64), 256, 0, stream>>>(xb, WeT, be, pe);
  // after enc gemm, xb is dead -> WdT may overwrite it (stream-ordered)
  k_cvt_T<<<dim3(DEC_COLS / 64, 1), 256, 0, stream>>>(Wd, WdT, L_L, DEC_COLS);
  k_enc_post<<<dim3(BATCH / 4), 256, 0, stream>>>(pe, ue, rr, h, lqe);
  k_dec_mfma<<<dim3(4, NTOT / 64), 256, 0, stream>>>(h, x, WdT, bd, Ld);
  k_final<<<dim3(1), 1024, 0, stream>>>(Ld, lqe, out);
}

// Round 3
// 134.127 us; speedup vs baseline: 2.5614x; 1.0462x over previous
//
#include <hip/hip_runtime.h>
#include <hip/hip_bf16.h>
#include <math.h>

#define D_L   256
#define L_L   64
#define K_C   8
#define BATCH 2048
#define NTOT  16384
#define ENC_COLS 1536
#define LOG2PI 1.8378770664093453f
#define L2E    1.4426950408889634f
#define LN2    0.6931471805599453f
#define C_HL2E 0.7213475204444817f   // 0.5 * log2(e)

typedef __attribute__((ext_vector_type(8)))  short short8;
typedef __attribute__((ext_vector_type(8)))  unsigned short ushort8;
typedef __attribute__((ext_vector_type(4)))  float float4_;
typedef __attribute__((ext_vector_type(16))) float float16_;

// fast exp2/log2 (v_exp_f32 / v_log_f32), with safe fallback
#if defined(__has_builtin)
#  if __has_builtin(__builtin_amdgcn_exp2f)
#    define EXP2F(x) __builtin_amdgcn_exp2f(x)
#  endif
#  if __has_builtin(__builtin_amdgcn_logf)
#    define LOG2F(x) __builtin_amdgcn_logf(x)
#  endif
#endif
#ifndef EXP2F
#  define EXP2F(x) __expf((x) * LN2)
#endif
#ifndef LOG2F
#  define LOG2F(x) (__logf(x) * L2E)
#endif

// workspace layout (float offsets); total ~16.25 MB (round-0 used 16.9 MB OK)
#define OFF_PE   0                               // 2048*1536 f32
#define OFF_H    (BATCH * ENC_COLS)              // 16384*64 bf16
#define OFF_WET  (OFF_H + NTOT * L_L / 2)        // 1536*256 bf16
#define OFF_WDT  (OFF_WET + ENC_COLS * D_L / 2)  // 6144*64 bf16 (swizzled blocks)
#define OFF_ACC  (OFF_WDT + 6144 * 64 / 2)       // 1 f32 accumulator

__device__ __forceinline__ unsigned short f2bf(float f) {
  unsigned u = __float_as_uint(f);
  return (unsigned short)((u + 0x7fffu + ((u >> 16) & 1u)) >> 16);
}

__device__ __forceinline__ void gll16(const void* g, void* l) {
  __builtin_amdgcn_global_load_lds(
      (const __attribute__((address_space(1))) unsigned int*)g,
      (__attribute__((address_space(3))) unsigned int*)l, 16, 0, 0);
}

// ---------------------------------------------------------------------------
// prep: [0,96) We^T cvt; [96,192) Wd^T cvt (swizzled, p/a scaled by log2e);
//       [192] zero accumulator. grid 193 x 256.
// ---------------------------------------------------------------------------
__global__ __launch_bounds__(256) void k_prep(
    const float* __restrict__ We, const float* __restrict__ Wd,
    unsigned short* __restrict__ WeT, unsigned short* __restrict__ WdT,
    float* __restrict__ accf)
{
  const int bid = blockIdx.x, t = threadIdx.x;
  if (bid < 96) {
    // We (256 x 1536) f32 -> WeT (1536 x 256) bf16
    __shared__ float tile[64][65];
    const int cb = bid % 24, rb = bid / 24;
    const int c0 = cb * 64, r0 = rb * 64;
    {
      const int tr = t >> 2, tc = (t & 3) * 16;
      const float* src = We + (size_t)(r0 + tr) * ENC_COLS + c0 + tc;
      #pragma unroll
      for (int i = 0; i < 4; ++i) {
        float4_ v = *(const float4_*)(src + 4 * i);
        #pragma unroll
        for (int j = 0; j < 4; ++j) tile[tr][tc + 4 * i + j] = v[j];
      }
    }
    __syncthreads();
    const int c = t >> 2, ks = (t & 3) * 16;
    ushort8 o0, o1;
    #pragma unroll
    for (int j = 0; j < 8; ++j) {
      o0[j] = f2bf(tile[ks + j][c]);
      o1[j] = f2bf(tile[ks + 8 + j][c]);
    }
    unsigned short* dst = WeT + (size_t)(c0 + c) * D_L + r0 + ks;
    *(ushort8*)dst = o0;
    *(ushort8*)(dst + 8) = o1;
  } else if (bid < 192) {
    // Wd (64 x 6144) -> WdT[comp][param][dt][c 64][chunk' 8][e 8] bf16,
    // chunk' = chunk ^ (c&7); p/a params scaled by log2(e).
    const int idx = bid - 96;
    const int comp = idx / 12, p = (idx % 12) >> 2, dt = idx & 3;
    const int c = t & 63, kg = t >> 6;
    const float scale = (p == 0) ? 1.0f : L2E;
    const float* src = Wd + (size_t)(kg * 16) * 6144 + p * 2048 + comp * 256 + dt * 64 + c;
    float v[16];
    #pragma unroll
    for (int i = 0; i < 16; ++i) v[i] = src[(size_t)i * 6144] * scale;
    unsigned short* base = WdT + ((((size_t)(comp * 3 + p) * 4 + dt) * 64 + c) << 6);
    #pragma unroll
    for (int j = 0; j < 2; ++j) {
      ushort8 o;
      #pragma unroll
      for (int e = 0; e < 8; ++e) o[e] = f2bf(v[j * 8 + e]);
      const int ch = (kg * 2 + j) ^ (c & 7);
      *(ushort8*)(base + ch * 8) = o;
    }
  } else {
    if (t == 0) accf[0] = 0.0f;
  }
}

// ---------------------------------------------------------------------------
// Encoder GEMM (32x32x16 MFMA): pe = x @ We + be. 64x64 tile, K chunks of 64.
// x converted f32->bf16 during staging. grid (24, 32) x 256.
// ---------------------------------------------------------------------------
__global__ __launch_bounds__(256) void k_enc(
    const float* __restrict__ x, const unsigned short* __restrict__ WeT,
    const float* __restrict__ be, float* __restrict__ pe)
{
  __shared__ __align__(16) unsigned short as_[64 * 72];
  __shared__ __align__(16) unsigned short bs_[64 * 72];
  const int t = threadIdx.x;
  const int w = t >> 6, l = t & 63;
  const int col = l & 31, q = l >> 5;
  const int rg = w >> 1, dg = w & 1;
  const int m0 = blockIdx.y * 64, c0 = blockIdx.x * 64;

  const float bias = be[c0 + dg * 32 + col];
  float16_ acc;
  #pragma unroll
  for (int e = 0; e < 16; ++e) acc[e] = bias;   // bias via accumulator init

  for (int kc = 0; kc < 4; ++kc) {
    if (kc) __syncthreads();
    #pragma unroll
    for (int p2 = 0; p2 < 2; ++p2) {
      const int ci = t + 256 * p2;
      const int row = ci >> 3, ch = ci & 7;
      const float* xs = x + (size_t)(m0 + row) * D_L + kc * 64 + ch * 8;
      float4_ v0 = *(const float4_*)xs;
      float4_ v1 = *(const float4_*)(xs + 4);
      ushort8 o;
      o[0] = f2bf(v0[0]); o[1] = f2bf(v0[1]); o[2] = f2bf(v0[2]); o[3] = f2bf(v0[3]);
      o[4] = f2bf(v1[0]); o[5] = f2bf(v1[1]); o[6] = f2bf(v1[2]); o[7] = f2bf(v1[3]);
      *(ushort8*)&as_[row * 72 + ch * 8] = o;
      *(ushort8*)&bs_[row * 72 + ch * 8] =
          *(const ushort8*)(WeT + (size_t)(c0 + row) * D_L + kc * 64 + ch * 8);
    }
    __syncthreads();
    const unsigned short* arow = &as_[(rg * 32 + col) * 72 + q * 8];
    const unsigned short* brow = &bs_[(dg * 32 + col) * 72 + q * 8];
    #pragma unroll
    for (int st = 0; st < 4; ++st) {
      short8 a = *(const short8*)(arow + st * 16);
      short8 b = *(const short8*)(brow + st * 16);
      acc = __builtin_amdgcn_mfma_f32_32x32x16_bf16(a, b, acc, 0, 0, 0);
    }
  }
  #pragma unroll
  for (int e = 0; e < 16; ++e) {
    const int row = (e & 3) + 8 * (e >> 2) + 4 * q;
    pe[(size_t)(m0 + rg * 32 + row) * ENC_COLS + c0 + dg * 32 + col] = acc[e];
  }
}

// ---------------------------------------------------------------------------
// Encoder post: sample + h (bf16, chunk-swizzled rows) + Σ(L_q - L_e) -> accf.
// One wave per batch row. grid 512 x 256.
// ---------------------------------------------------------------------------
__global__ __launch_bounds__(256) void k_enc_post(
    const float* __restrict__ pe, const float* __restrict__ ue,
    const float* __restrict__ rr, unsigned short* __restrict__ h,
    float* __restrict__ accf)
{
  const int lane = threadIdx.x & 63;
  const int w = threadIdx.x >> 6;
  const int b = blockIdx.x * 4 + w;
  const float* row = pe + (size_t)b * ENC_COLS + lane;

  float m[8], p[8], a[8];
  #pragma unroll
  for (int k = 0; k < K_C; ++k) {
    m[k] = row[k * 64]; p[k] = row[512 + k * 64]; a[k] = row[1024 + k * 64];
  }
  float amax = a[0];
  #pragma unroll
  for (int k = 1; k < K_C; ++k) amax = fmaxf(amax, a[k]);
  float sa = 0.f;
  #pragma unroll
  for (int k = 0; k < K_C; ++k) sa += __expf(a[k] - amax);
  const float lse_a = amax + __logf(sa);

  float cum[8];
  {
    float cs = 0.f;
    #pragma unroll
    for (int k = 0; k < K_C; ++k) { cs += __expf(a[k] - lse_a); cum[k] = cs; }
  }
  float ep[8];
  #pragma unroll
  for (int k = 0; k < K_C; ++k) ep[k] = __expf(p[k]);

  // swizzled position within the 128B row (matches decoder A-frag reads)
  const int sw = ((((lane >> 3) ^ (b & 7)) << 3) | (lane & 7));

  float tot = 0.f;
  for (int j = 0; j < 8; ++j) {
    const int n = b + BATCH * j;
    const float rv = rr[(size_t)n * L_L + lane];
    const float uv = ue[(size_t)n * L_L + lane];
    int idx = 0;
    #pragma unroll
    for (int k = 0; k < K_C; ++k) idx += (rv > cum[k]) ? 1 : 0;
    idx = min(idx, K_C - 1);
    float msel = m[0], psel = p[0];
    #pragma unroll
    for (int k = 1; k < K_C; ++k) {
      const bool sel = (idx == k);
      msel = sel ? m[k] : msel;
      psel = sel ? p[k] : psel;
    }
    const float hv = fmaf(__expf(-0.5f * psel), uv, msel);
    h[(size_t)n * L_L + sw] = f2bf(hv);

    float st = 0.f;
    #pragma unroll
    for (int k = 0; k < K_C; ++k) {
      const float dd = hv - m[k];
      const float tt = a[k] + 0.5f * p[k] - 0.5f * ep[k] * dd * dd;
      st += __expf(tt);
    }
    tot += -0.5f * hv * hv - (__logf(st + 1e-30f) - lse_a);
  }
  #pragma unroll
  for (int off = 1; off < 64; off <<= 1) tot += __shfl_xor(tot, off, 64);
  __shared__ float red2[4];
  if (lane == 0) red2[w] = tot;
  __syncthreads();
  if (threadIdx.x == 0) atomicAdd(accf, red2[0] + red2[1] + red2[2] + red2[3]);
}

// ---------------------------------------------------------------------------
// Decoder: fused bf16 MFMA GEMM + mixture epilogue.
// Block = 128 rows x 64 d (2 n-tiles), async double-buffered B staging.
// grid (4, 128) x 256.
// ---------------------------------------------------------------------------
__global__ __launch_bounds__(256, 2) void k_dec(
    const unsigned short* __restrict__ hb, const float* __restrict__ x,
    const unsigned short* __restrict__ WdT, const float* __restrict__ bd,
    float* __restrict__ accf)
{
  __shared__ __align__(16) unsigned short hs[128 * 64];        // 16 KB
  __shared__ __align__(16) unsigned short bT[2][3 * 64 * 64];  // 2 x 24 KB
  __shared__ float biasLds[1536];                              // 6 KB

  const int t = threadIdx.x;
  const int w = t >> 6, l = t & 63;
  const int col = l & 31, q = l >> 5, c7 = col & 7;
  const int rg = w >> 1, dg = w & 1;
  const int dt = blockIdx.x, d0 = dt * 64;
  const int n0 = blockIdx.y * 128;

  // async-stage A: 128 rows x 128B, contiguous (pre-swizzled by enc_post)
  {
    const char* hg = (const char*)hb + (size_t)n0 * 128;
    #pragma unroll
    for (int j = 0; j < 4; ++j) {
      const int cj = (w << 2) | j;
      gll16(hg + cj * 1024 + l * 16, (char*)hs + cj * 1024);
    }
  }
  // async-stage B comp 0 -> buf 0
  #pragma unroll
  for (int p = 0; p < 3; ++p) {
    const char* gsrc = (const char*)WdT + (((size_t)p * 4 + dt) << 13);
    #pragma unroll
    for (int j = 0; j < 2; ++j) {
      const int cj = (w << 1) | j;
      gll16(gsrc + cj * 1024 + l * 16, (char*)bT[0] + p * 8192 + cj * 1024);
    }
  }
  // bias (p/a pre-scaled by log2e)
  #pragma unroll
  for (int i = 0; i < 6; ++i) {
    const int idx = t + 256 * i;
    const int pp = idx >> 9, comp = (idx >> 6) & 7, d = idx & 63;
    float v = bd[pp * 2048 + comp * 256 + d0 + d];
    if (pp) v *= L2E;
    biasLds[idx] = v;
  }
  // x preload (L2-resident)
  float xv[2][16];
  #pragma unroll
  for (int t2 = 0; t2 < 2; ++t2)
    #pragma unroll
    for (int e = 0; e < 16; ++e) {
      const int rw = (e & 3) + 8 * (e >> 2) + 4 * q;
      const int n = n0 + t2 * 64 + rg * 32 + rw;
      xv[t2][e] = x[(size_t)(n & (BATCH - 1)) * D_L + d0 + dg * 32 + col];
    }

  __syncthreads();  // barrier drain waits vmcnt(0): hs + bT[0] ready

  // hoist A fragments (reused across all 8 comps)
  short8 af[2][4];
  #pragma unroll
  for (int t2 = 0; t2 < 2; ++t2)
    #pragma unroll
    for (int st = 0; st < 4; ++st) {
      const int ch = ((st * 2 + q) ^ c7);
      af[t2][st] = *(const short8*)((const char*)hs + t2 * 8192 +
                                    (rg * 32 + col) * 128 + ch * 16);
    }

  float s_a[2][16], s_t[2][16];
  #pragma unroll
  for (int t2 = 0; t2 < 2; ++t2)
    #pragma unroll
    for (int e = 0; e < 16; ++e) { s_a[t2][e] = 0.f; s_t[t2][e] = 0.f; }

  const int browoff = (dg * 32 + col) * 128;  // bytes within a param block

  for (int kc = 0; kc < K_C; ++kc) {
    if (kc < 7) {  // prefetch next comp into other buffer (in flight over compute)
      #pragma unroll
      for (int p = 0; p < 3; ++p) {
        const char* gsrc = (const char*)WdT + (((size_t)((kc + 1) * 3 + p) * 4 + dt) << 13);
        #pragma unroll
        for (int j = 0; j < 2; ++j) {
          const int cj = (w << 1) | j;
          gll16(gsrc + cj * 1024 + l * 16,
                (char*)bT[(kc + 1) & 1] + p * 8192 + cj * 1024);
        }
      }
    }
    const float bm = biasLds[kc * 64 + dg * 32 + col];
    const float bp = biasLds[512 + kc * 64 + dg * 32 + col];
    const float ba = biasLds[1024 + kc * 64 + dg * 32 + col];
    const char* bbuf = (const char*)bT[kc & 1];

    #pragma unroll
    for (int t2 = 0; t2 < 2; ++t2) {
      float16_ am, ap, aa;
      #pragma unroll
      for (int e = 0; e < 16; ++e) { am[e] = bm; ap[e] = bp; aa[e] = ba; }
      #pragma unroll
      for (int st = 0; st < 4; ++st) {
        const int ch = ((st * 2 + q) ^ c7) * 16;
        short8 wm_ = *(const short8*)(bbuf + browoff + ch);
        short8 wp_ = *(const short8*)(bbuf + 8192 + browoff + ch);
        short8 wa_ = *(const short8*)(bbuf + 16384 + browoff + ch);
        am = __builtin_amdgcn_mfma_f32_32x32x16_bf16(af[t2][st], wm_, am, 0, 0, 0);
        ap = __builtin_amdgcn_mfma_f32_32x32x16_bf16(af[t2][st], wp_, ap, 0, 0, 0);
        aa = __builtin_amdgcn_mfma_f32_32x32x16_bf16(af[t2][st], wa_, aa, 0, 0, 0);
      }
      // ap/aa are in log2 units (weights+bias pre-scaled): 1 v_exp each
      #pragma unroll
      for (int e = 0; e < 16; ++e) {
        const float dd = xv[t2][e] - am[e];
        const float ex2 = EXP2F(ap[e]);                 // = e^{logp}
        const float t1 = fmaf(0.5f, ap[e], aa[e]);
        const float ttL = fmaf(-C_HL2E * ex2, dd * dd, t1);
        s_a[t2][e] += EXP2F(aa[e]);
        s_t[t2][e] += EXP2F(ttL);
      }
    }
    __syncthreads();  // drains prefetch vmcnt; separates buffer reuse
  }

  // block reduction -> single atomic
  float v = 0.f;
  #pragma unroll
  for (int t2 = 0; t2 < 2; ++t2)
    #pragma unroll
    for (int e = 0; e < 16; ++e)
      v += LOG2F(s_t[t2][e] + 1e-30f) - LOG2F(s_a[t2][e]);
  v *= LN2;
  #pragma unroll
  for (int off = 1; off < 64; off <<= 1) v += __shfl_xor(v, off, 64);
  float* red = (float*)hs;  // hs dead after A-frag hoist
  if (l == 0) red[w] = v;
  __syncthreads();
  if (t == 0) atomicAdd(accf, red[0] + red[1] + red[2] + red[3]);
}

// ---------------------------------------------------------------------------
__global__ void k_final(const float* __restrict__ accf, float* __restrict__ out)
{
  if (threadIdx.x == 0) out[0] = -(accf[0] / (float)NTOT) + 128.0f * LOG2PI;
}

// ---------------------------------------------------------------------------
extern "C" void kernel_launch(void* const* d_in, const int* in_sizes, int n_in,
                              void* d_out, int out_size, void* d_ws, size_t ws_size,
                              hipStream_t stream)
{
  const float* x  = (const float*)d_in[0];
  const float* We = (const float*)d_in[1];
  const float* be = (const float*)d_in[2];
  const float* Wd = (const float*)d_in[3];
  const float* bd = (const float*)d_in[4];
  const float* ue = (const float*)d_in[5];
  const float* rr = (const float*)d_in[6];
  float* out = (float*)d_out;

  float* ws = (float*)d_ws;
  float* pe           = ws + OFF_PE;
  unsigned short* h   = (unsigned short*)(ws + OFF_H);
  unsigned short* WeT = (unsigned short*)(ws + OFF_WET);
  unsigned short* WdT = (unsigned short*)(ws + OFF_WDT);
  float* accf         = ws + OFF_ACC;

  k_prep<<<dim3(193), 256, 0, stream>>>(We, Wd, WeT, WdT, accf);
  k_enc<<<dim3(ENC_COLS / 64, BATCH / 64), 256, 0, stream>>>(x, WeT, be, pe);
  k_enc_post<<<dim3(BATCH / 4), 256, 0, stream>>>(pe, ue, rr, h, accf);
  k_dec<<<dim3(4, NTOT / 128), 256, 0, stream>>>(h, x, WdT, bd, accf);
  k_final<<<dim3(1), 64, 0, stream>>>(accf, out);
}

// Round 5
// 123.809 us; speedup vs baseline: 2.7749x; 1.0833x over previous
//
#include <hip/hip_runtime.h>
#include <hip/hip_bf16.h>
#include <math.h>

#define D_L   256
#define L_L   64
#define K_C   8
#define BATCH 2048
#define NTOT  16384
#define ENC_COLS 1536
#define LOG2PI 1.8378770664093453f
#define L2E    1.4426950408889634f
#define LN2    0.6931471805599453f
#define C_HL2E 0.7213475204444817f   // 0.5 * log2(e)

typedef __attribute__((ext_vector_type(8)))  short short8;
typedef __attribute__((ext_vector_type(8)))  unsigned short ushort8;
typedef __attribute__((ext_vector_type(4)))  unsigned short ushort4_;
typedef __attribute__((ext_vector_type(4)))  float float4_;
typedef __attribute__((ext_vector_type(16))) float float16_;

#if defined(__has_builtin)
#  if __has_builtin(__builtin_amdgcn_exp2f)
#    define EXP2F(x) __builtin_amdgcn_exp2f(x)
#  endif
#  if __has_builtin(__builtin_amdgcn_logf)
#    define LOG2F(x) __builtin_amdgcn_logf(x)
#  endif
#endif
#ifndef EXP2F
#  define EXP2F(x) __expf((x) * LN2)
#endif
#ifndef LOG2F
#  define LOG2F(x) (__logf(x) * L2E)
#endif

// workspace layout (float offsets), total ~16.25 MB
#define OFF_PE    0                                 // 2048*1536 f32
#define OFF_H     (BATCH * ENC_COLS)                // 16384*64 bf16, MFMA-A-frag order
#define OFF_WET2  (OFF_H + NTOT * L_L / 2)          // 1536*256 bf16, B-frag order
#define OFF_WDT2  (OFF_WET2 + ENC_COLS * D_L / 2)   // 6144*64 bf16, B-frag order
#define OFF_ACC   (OFF_WDT2 + 6144 * 64 / 2)        // 1 f32

__device__ __forceinline__ unsigned short f2bf(float f) {
  unsigned u = __float_as_uint(f);
  return (unsigned short)((u + 0x7fffu + ((u >> 16) & 1u)) >> 16);
}

// ---------------------------------------------------------------------------
// prep: 192 uniform 64x64 tile blocks converting W's into MFMA-B-fragment
// order bf16, + 1 block zeroing accf. Fragment order per 64x64 (k x col) tile:
//   [dg 2][st 4][q 2][col 32][j 8], element = W[k = st*16+q*8+j][dg*32+col]
// so a wave's 64 lanes read one contiguous 1 KB run per (dg,st).
//   tiles 0..95:   Wd tile (comp,p,dt), cols p*2048+comp*256+dt*64, scale L2E on p>0
//   tiles 96..191: We tile (cblk,kc),  rows kc*64, cols cblk*64
// ---------------------------------------------------------------------------
__global__ __launch_bounds__(256) void k_prep(
    const float* __restrict__ We, const float* __restrict__ Wd,
    unsigned short* __restrict__ WeT2, unsigned short* __restrict__ WdT2,
    float* __restrict__ accf)
{
  const int bid = blockIdx.x, t = threadIdx.x;
  if (bid == 192) { if (t == 0) accf[0] = 0.0f; return; }

  const float* src; int C, rowbase, colbase; float scale;
  unsigned short* dst;
  if (bid < 96) {
    const int comp = bid / 12, p = (bid % 12) >> 2, dt = bid & 3;
    src = Wd; C = 6144; rowbase = 0;
    colbase = p * 2048 + comp * 256 + dt * 64;
    scale = p ? L2E : 1.0f;
    dst = WdT2 + (size_t)bid * 4096;            // tile idx == (comp*3+p)*4+dt == bid
  } else {
    const int idx = bid - 96;
    src = We; C = ENC_COLS; rowbase = (idx & 3) * 64;
    colbase = (idx >> 2) * 64;
    scale = 1.0f;
    dst = WeT2 + (size_t)idx * 4096;            // tile idx == cblk*4+kc
  }

  __shared__ float tile[64][65];
  {
    const int col = t & 63, w0 = t >> 6;
    #pragma unroll
    for (int i = 0; i < 16; ++i) {
      const int r = w0 + i * 4;
      tile[r][col] = src[(size_t)(rowbase + r) * C + colbase + col] * scale;
    }
  }
  __syncthreads();
  const int st = t >> 6, q = (t >> 5) & 1, c = t & 31;
  #pragma unroll
  for (int dg = 0; dg < 2; ++dg) {
    ushort8 o;
    #pragma unroll
    for (int j = 0; j < 8; ++j) o[j] = f2bf(tile[st * 16 + q * 8 + j][dg * 32 + c]);
    *(ushort8*)(dst + ((((size_t)dg * 4 + st) * 2 + q) * 32 + c) * 8) = o;
  }
}

// ---------------------------------------------------------------------------
// Encoder GEMM: pe = x @ We + be. 64x64 tile, full K=256 staged in LDS once
// (single barrier), B-fragments streamed from L2. grid (24, 32) x 256.
// ---------------------------------------------------------------------------
__global__ __launch_bounds__(256) void k_enc(
    const float* __restrict__ x, const unsigned short* __restrict__ WeT2,
    const float* __restrict__ be, float* __restrict__ pe)
{
  __shared__ __align__(16) unsigned short as_[64 * 264];
  const int t = threadIdx.x;
  const int w = t >> 6, l = t & 63;
  const int col = l & 31, q = l >> 5;
  const int rg = w >> 1, dg = w & 1;
  const int m0 = blockIdx.y * 64, cblk = blockIdx.x, c0 = cblk * 64;

  // stage x tile (64 rows x 256 k) f32 -> bf16, coalesced
  {
    const int kc4 = (t & 63) * 4;
    #pragma unroll
    for (int i = 0; i < 16; ++i) {
      const int r = (t >> 6) + i * 4;
      float4_ v = *(const float4_*)(x + (size_t)(m0 + r) * D_L + kc4);
      ushort4_ o;
      o[0] = f2bf(v[0]); o[1] = f2bf(v[1]); o[2] = f2bf(v[2]); o[3] = f2bf(v[3]);
      *(ushort4_*)&as_[r * 264 + kc4] = o;
    }
  }

  const float bias = be[c0 + dg * 32 + col];
  float16_ acc;
  #pragma unroll
  for (int e = 0; e < 16; ++e) acc[e] = bias;

  __syncthreads();  // the only barrier

  const unsigned short* arow = &as_[(rg * 32 + col) * 264 + q * 8];
  const unsigned short* bbase = WeT2 + (size_t)cblk * 16384 + dg * 2048 + l * 8;
  #pragma unroll
  for (int kc = 0; kc < 4; ++kc) {
    #pragma unroll
    for (int st = 0; st < 4; ++st) {
      short8 a = *(const short8*)(arow + kc * 64 + st * 16);
      short8 b = *(const short8*)(bbase + (size_t)kc * 4096 + st * 512);
      acc = __builtin_amdgcn_mfma_f32_32x32x16_bf16(a, b, acc, 0, 0, 0);
    }
  }
  #pragma unroll
  for (int e = 0; e < 16; ++e) {
    const int row = (e & 3) + 8 * (e >> 2) + 4 * q;
    pe[(size_t)(m0 + rg * 32 + row) * ENC_COLS + c0 + dg * 32 + col] = acc[e];
  }
}

// ---------------------------------------------------------------------------
// Encoder post: sample + h (bf16, decoder-A-fragment global order) + Σ(Lq-Le).
// One wave per batch row. grid 512 x 256.
// h layout: [nblk 256][rg 2][st 4][q 2][col 32][j 8]
// ---------------------------------------------------------------------------
__global__ __launch_bounds__(256) void k_enc_post(
    const float* __restrict__ pe, const float* __restrict__ ue,
    const float* __restrict__ rr, unsigned short* __restrict__ h,
    float* __restrict__ accf)
{
  const int lane = threadIdx.x & 63;
  const int w = threadIdx.x >> 6;
  const int b = blockIdx.x * 4 + w;
  const float* row = pe + (size_t)b * ENC_COLS + lane;

  float m[8], p[8], a[8];
  #pragma unroll
  for (int k = 0; k < K_C; ++k) {
    m[k] = row[k * 64]; p[k] = row[512 + k * 64]; a[k] = row[1024 + k * 64];
  }
  float amax = a[0];
  #pragma unroll
  for (int k = 1; k < K_C; ++k) amax = fmaxf(amax, a[k]);
  float sa = 0.f;
  #pragma unroll
  for (int k = 0; k < K_C; ++k) sa += __expf(a[k] - amax);
  const float lse_a = amax + __logf(sa);

  float cum[8];
  {
    float cs = 0.f;
    #pragma unroll
    for (int k = 0; k < K_C; ++k) { cs += __expf(a[k] - lse_a); cum[k] = cs; }
  }
  float ep[8];
  #pragma unroll
  for (int k = 0; k < K_C; ++k) ep[k] = __expf(p[k]);

  // this lane's fragment slot within a row's 64 k-values
  const int st = lane >> 4, qq = (lane >> 3) & 1, jj = lane & 7;

  float tot = 0.f;
  for (int j = 0; j < 8; ++j) {
    const int n = b + BATCH * j;
    const float rv = rr[(size_t)n * L_L + lane];
    const float uv = ue[(size_t)n * L_L + lane];
    int idx = 0;
    #pragma unroll
    for (int k = 0; k < K_C; ++k) idx += (rv > cum[k]) ? 1 : 0;
    idx = min(idx, K_C - 1);
    float msel = m[0], psel = p[0];
    #pragma unroll
    for (int k = 1; k < K_C; ++k) {
      const bool sel = (idx == k);
      msel = sel ? m[k] : msel;
      psel = sel ? p[k] : psel;
    }
    const float hv = fmaf(__expf(-0.5f * psel), uv, msel);

    const int nblk = n >> 6, rgn = (n >> 5) & 1, coln = n & 31;
    h[((((size_t)(nblk * 2 + rgn) * 4 + st) * 2 + qq) * 32 + coln) * 8 + jj] = f2bf(hv);

    float stt = 0.f;
    #pragma unroll
    for (int k = 0; k < K_C; ++k) {
      const float dd = hv - m[k];
      const float tt = a[k] + 0.5f * p[k] - 0.5f * ep[k] * dd * dd;
      stt += __expf(tt);
    }
    tot += -0.5f * hv * hv - (__logf(stt + 1e-30f) - lse_a);
  }
  #pragma unroll
  for (int off = 1; off < 64; off <<= 1) tot += __shfl_xor(tot, off, 64);
  __shared__ float red2[4];
  if (lane == 0) red2[w] = tot;
  __syncthreads();
  if (threadIdx.x == 0) atomicAdd(accf, red2[0] + red2[1] + red2[2] + red2[3]);
}

// ---------------------------------------------------------------------------
// Decoder: barrier-free fused MFMA GEMM + mixture epilogue.
// Block = 64 rows x 64 d, 4 waves (rg,dg), all fragments register-direct from
// L2 (h and WdT2 pre-arranged in fragment order). No LDS in the hot loop.
// grid (4, 256) x 256.
// ---------------------------------------------------------------------------
__global__ __launch_bounds__(256, 2) void k_dec(
    const unsigned short* __restrict__ hF, const float* __restrict__ x,
    const unsigned short* __restrict__ WdT2, const float* __restrict__ bd,
    float* __restrict__ accf)
{
  const int t = threadIdx.x;
  const int w = t >> 6, l = t & 63;
  const int col = l & 31, q = l >> 5;
  const int rg = w >> 1, dg = w & 1;
  const int dt = blockIdx.x, d0 = dt * 64;
  const int nblk = blockIdx.y, n0 = nblk * 64;
  const int colD = d0 + dg * 32 + col;

  // A fragments: 4 coalesced 16B loads (1 KB per wave per load)
  const unsigned short* hbase = hF + ((size_t)(nblk * 2 + rg) * 4) * 512 + l * 8;
  short8 af[4];
  #pragma unroll
  for (int st = 0; st < 4; ++st) af[st] = *(const short8*)(hbase + st * 512);

  // x values for this lane's 16 C-elements (reused across all comps)
  float xv[16];
  #pragma unroll
  for (int e = 0; e < 16; ++e) {
    const int rw = (e & 3) + 8 * (e >> 2) + 4 * q;
    const int n = n0 + rg * 32 + rw;
    xv[e] = x[(size_t)(n & (BATCH - 1)) * D_L + colD];
  }

  float s_a[16], s_t[16];
  #pragma unroll
  for (int e = 0; e < 16; ++e) { s_a[e] = 0.f; s_t[e] = 0.f; }

  const unsigned short* wbase = WdT2 + dg * 2048 + l * 8;

  for (int comp = 0; comp < K_C; ++comp) {
    const float bm  = bd[comp * 256 + colD];
    const float bpL = bd[2048 + comp * 256 + colD] * L2E;
    const float baL = bd[4096 + comp * 256 + colD] * L2E;

    // 12 coalesced B-fragment loads, all independent (deep ILP, no barrier)
    short8 bf[3][4];
    #pragma unroll
    for (int p = 0; p < 3; ++p) {
      const unsigned short* pb = wbase + ((size_t)(comp * 3 + p) * 4 + dt) * 4096;
      #pragma unroll
      for (int st = 0; st < 4; ++st) bf[p][st] = *(const short8*)(pb + st * 512);
    }

    float16_ am = {}, ap = {}, aa = {};
    #pragma unroll
    for (int st = 0; st < 4; ++st) {
      am = __builtin_amdgcn_mfma_f32_32x32x16_bf16(af[st], bf[0][st], am, 0, 0, 0);
      ap = __builtin_amdgcn_mfma_f32_32x32x16_bf16(af[st], bf[1][st], ap, 0, 0, 0);
      aa = __builtin_amdgcn_mfma_f32_32x32x16_bf16(af[st], bf[2][st], aa, 0, 0, 0);
    }

    #pragma unroll
    for (int e = 0; e < 16; ++e) {
      const float dd  = xv[e] - (am[e] + bm);
      const float lpL = ap[e] + bpL;
      const float laL = aa[e] + baL;
      const float ex2 = EXP2F(lpL);                        // = e^{logp}
      const float t1  = fmaf(0.5f, lpL, laL);
      const float ttL = fmaf(-C_HL2E * ex2, dd * dd, t1);
      s_a[e] += EXP2F(laL);
      s_t[e] += EXP2F(ttL);
    }
  }

  float v = 0.f;
  #pragma unroll
  for (int e = 0; e < 16; ++e)
    v += LOG2F(s_t[e] + 1e-30f) - LOG2F(s_a[e]);
  v *= LN2;
  #pragma unroll
  for (int off = 1; off < 64; off <<= 1) v += __shfl_xor(v, off, 64);
  __shared__ float red[4];
  if (l == 0) red[w] = v;
  __syncthreads();
  if (t == 0) atomicAdd(accf, red[0] + red[1] + red[2] + red[3]);
}

// ---------------------------------------------------------------------------
__global__ void k_final(const float* __restrict__ accf, float* __restrict__ out)
{
  if (threadIdx.x == 0) out[0] = -(accf[0] / (float)NTOT) + 128.0f * LOG2PI;
}

// ---------------------------------------------------------------------------
extern "C" void kernel_launch(void* const* d_in, const int* in_sizes, int n_in,
                              void* d_out, int out_size, void* d_ws, size_t ws_size,
                              hipStream_t stream)
{
  const float* x  = (const float*)d_in[0];
  const float* We = (const float*)d_in[1];
  const float* be = (const float*)d_in[2];
  const float* Wd = (const float*)d_in[3];
  const float* bd = (const float*)d_in[4];
  const float* ue = (const float*)d_in[5];
  const float* rr = (const float*)d_in[6];
  float* out = (float*)d_out;

  float* ws = (float*)d_ws;
  float* pe            = ws + OFF_PE;
  unsigned short* h    = (unsigned short*)(ws + OFF_H);
  unsigned short* WeT2 = (unsigned short*)(ws + OFF_WET2);
  unsigned short* WdT2 = (unsigned short*)(ws + OFF_WDT2);
  float* accf          = ws + OFF_ACC;

  k_prep<<<dim3(193), 256, 0, stream>>>(We, Wd, WeT2, WdT2, accf);
  k_enc<<<dim3(ENC_COLS / 64, BATCH / 64), 256, 0, stream>>>(x, WeT2, be, pe);
  k_enc_post<<<dim3(BATCH / 4), 256, 0, stream>>>(pe, ue, rr, h, accf);
  k_dec<<<dim3(4, NTOT / 64), 256, 0, stream>>>(h, x, WdT2, bd, accf);
  k_final<<<dim3(1), 64, 0, stream>>>(accf, out);
}